// Round 5
// baseline (18846.384 us; speedup 1.0000x reference)
//
#include <hip/hip_runtime.h>
#include <cstdint>
#include <cstddef>

#define LSEQ 512
#define NBLK 192
#define ASZ (128*256*8)   // halfs per h parity plane (512 KB)

typedef _Float16 f16;
typedef f16 f16x8 __attribute__((ext_vector_type(8)));
typedef float f32x4 __attribute__((ext_vector_type(4)));
typedef unsigned long long u64t;

#define MFMA16(a, b, c) __builtin_amdgcn_mfma_f32_16x16x32_f16(a, b, c, 0, 0, 0)

static __device__ __forceinline__ float sigm(float x){ return 1.f/(1.f+__expf(-x)); }
static __device__ __forceinline__ float tanh_f(float x){
    x = fminf(fmaxf(x,-15.f),15.f);
    float t = __expf(-2.f*x);
    return (1.f-t)/(1.f+t);
}
static __device__ __forceinline__ f16x8 cvt8(const float* s){
    float4 a = *(const float4*)s, b = *(const float4*)(s+4);
    f16x8 v = {(f16)a.x,(f16)a.y,(f16)a.z,(f16)a.w,(f16)b.x,(f16)b.y,(f16)b.z,(f16)b.w};
    return v;
}

// ---- R5: async global->LDS DMA (no VGPR staging, no scratch). R0's reg-
// staged prefetch was pinned at ~14 GB/s/CU regardless of depth (R2) or
// cache mode (R4) -- consistent with st[] spilling at VGPR_Count=256 (w1
// alone = 256 VGPRs), which serializes every chunk on a scratch round trip.
// global_load_lds writes LDS at wave-uniform-base + lane*16; our layout
// (row stride 2064/4112, 16B aligned, 64-lane contiguous runs) satisfies it.
// aux 0x11 = SC0|SC1: served at the IC coherence point (R0-proven for
// cross-block h visibility).
typedef const __attribute__((address_space(1))) char gchar;
typedef __attribute__((address_space(3))) char lchar;
static __device__ __forceinline__ void dma16(const char* g, char* l){
    __builtin_amdgcn_global_load_lds((gchar*)g, (lchar*)l, 16, 0, 0x11);
}
// 8B IC-coherent atomic ops (h stores + final read + barrier).
static __device__ __forceinline__ u64t hload(const u64t* p){
    return __hip_atomic_load(p, __ATOMIC_RELAXED, __HIP_MEMORY_SCOPE_AGENT);
}
static __device__ __forceinline__ void hstore(u64t* p, u64t v){
    __hip_atomic_store(p, v, __ATOMIC_RELAXED, __HIP_MEMORY_SCOPE_AGENT);
}
union U64F16 { u64t q; f16 h[4]; };
union U2F16x8 { u64t q[2]; f16x8 v; };

// Chunk sync: wait for this chunk's DMAs (leave newer ones in flight), then
// barrier. vmcnt(8)=2 newer chunks x 4 DMA-instr in flight; tail drains.
#define WAITVM8() __builtin_amdgcn_s_waitcnt(0x0F78)
#define WAITVM4() __builtin_amdgcn_s_waitcnt(0x0F74)
#define WAITVM0() __builtin_amdgcn_s_waitcnt(0x0F70)

// Single-level grid barrier (R0-proven; 2-level was neutral).
static __device__ __forceinline__ void grid_barrier(int* bar){
    WAITVM0();                // vmcnt(0): h stores acked at IC, DMAs retired
    __syncthreads();
    if (threadIdx.x == 0){
        int g = __hip_atomic_load(&bar[32], __ATOMIC_RELAXED, __HIP_MEMORY_SCOPE_AGENT);
        int old = __hip_atomic_fetch_add(&bar[0], 1, __ATOMIC_RELAXED, __HIP_MEMORY_SCOPE_AGENT);
        if (old == NBLK - 1){
            __hip_atomic_store(&bar[0], 0, __ATOMIC_RELAXED, __HIP_MEMORY_SCOPE_AGENT);
            __hip_atomic_store(&bar[32], g + 1, __ATOMIC_RELAXED, __HIP_MEMORY_SCOPE_AGENT);
        } else {
            while (__hip_atomic_load(&bar[32], __ATOMIC_RELAXED, __HIP_MEMORY_SCOPE_AGENT) == g)
                __builtin_amdgcn_s_sleep(2);
        }
    }
    __syncthreads();
}

// Blocks 0..127: L1 (mh=blk>>6 m-half 128 rows, nb=blk&63 -> 16 j-cols x 4 gates).
// Blocks 128..191: L0 (all 256 rows, nb -> 16 j-cols x 4 gates).
// Waves: nh=wav&1 (col-half, 32 gate-cols), kh=wav>>1 (K-half).
// Weights VGPR/AGPR-resident fp16 frags; h planes [kc8][m 256][8] fp16, 2
// parity slots. 32 chunks/step, 4 LDS buffers, DMA prefetch depth 3.
__global__ void __launch_bounds__(256, 1) lstm_persist(
    const float* __restrict__ seq,
    const float* __restrict__ Wih0, const float* __restrict__ Whh0,
    const float* __restrict__ bih0, const float* __restrict__ bhh0,
    const float* __restrict__ Wih1, const float* __restrict__ Whh1,
    const float* __restrict__ bih1, const float* __restrict__ bhh1,
    const float* __restrict__ linW, const float* __restrict__ linb,
    f16* __restrict__ A0, f16* __restrict__ A1, float* __restrict__ out,
    int* __restrict__ bar)
{
    __shared__ char  pool[66048] __attribute__((aligned(16)));
    __shared__ float ldsX[1536];
    __shared__ float ldsWx[384];
    __shared__ float ldsBias[64];
    float* poolf = (float*)pool;

    const int tid = threadIdx.x, lane = tid & 63, wav = tid >> 6;
    const int quad = lane >> 4, l15 = lane & 15;
    const int nh = wav & 1, kh = wav >> 1;
    const int blk = blockIdx.x;

    if (blk < 128){
        // ======================= L1 =======================
        const int mh = blk >> 6, nb = blk & 63;
        const int m0 = mh * 128, j0 = nb * 16;
        if (tid < 64){
            int R = (tid >> 4) * 1024 + j0 + (tid & 15);
            ldsBias[tid] = bih1[R] + bhh1[R];
        }
        // weights: w1[kg][nt], k = kh*1024 + kg*32 + quad*8 (kh=0 -> Wih1, kh=1 -> Whh1)
        f16x8 w1[32][2];
        {
            const float* Wsrc = kh ? Whh1 : Wih1;
            #pragma unroll
            for (int nt = 0; nt < 2; ++nt){
                int ct = nh * 32 + nt * 16 + l15;
                size_t Roff = (size_t)((ct >> 4) * 1024 + j0 + (ct & 15)) * 1024;
                #pragma unroll
                for (int kg = 0; kg < 32; ++kg)
                    w1[kg][nt] = cvt8(Wsrc + Roff + kg * 32 + quad * 8);
            }
        }
        float c1[8] = {0,0,0,0,0,0,0,0};

        for (int p = 0; p <= LSEQ; ++p){
            if (p >= 1){
                const char* P0 = (const char*)(A0 + (size_t)((p + 1) & 1) * ASZ); // h0[p-1]
                const char* P1 = (const char*)(A1 + (size_t)(p & 1) * ASZ);       // h1[p-2]
                u64t* W1p = (u64t*)(A1 + (size_t)((p + 1) & 1) * ASZ);            // h1[p-1]

                f32x4 acc[8][2];
                #pragma unroll
                for (int a = 0; a < 8; ++a){ acc[a][0] = (f32x4){0,0,0,0}; acc[a][1] = (f32x4){0,0,0,0}; }

                // prologue: DMA chunks 0..2 (all < 16 -> P0)
                #pragma unroll
                for (int n = 0; n < 3; ++n)
                    #pragma unroll
                    for (int i = 0; i < 4; ++i){
                        int idx = i * 256 + tid, kc8l = idx >> 7, ml = idx & 127;
                        dma16(P0 + (size_t)(((n * 8 + kc8l) * 256 + m0 + ml) * 16),
                              pool + n * 16512 + kc8l * 2064 + ml * 16);
                    }
                #pragma unroll
                for (int c = 0; c < 32; ++c){
                    if (c <= 29) WAITVM8(); else if (c == 30) WAITVM4(); else WAITVM0();
                    __builtin_amdgcn_s_barrier();             // chunk c resident for all waves
                    if (c < 29){
                        const int n = c + 3;
                        const char* P = (n < 16) ? P0 : P1;
                        const int kb = (n < 16) ? n * 8 : (n - 16) * 8;
                        #pragma unroll
                        for (int i = 0; i < 4; ++i){
                            int idx = i * 256 + tid, kc8l = idx >> 7, ml = idx & 127;
                            dma16(P + (size_t)(((kb + kc8l) * 256 + m0 + ml) * 16),
                                  pool + (n & 3) * 16512 + kc8l * 2064 + ml * 16);
                        }
                    }
                    if (kh == (c >> 4)){
                        const char* la = pool + (c & 3) * 16512;
                        const int cl = c & 15;
                        #pragma unroll
                        for (int kgl = 0; kgl < 2; ++kgl){
                            const int ckg = cl * 2 + kgl;
                            #pragma unroll
                            for (int mt = 0; mt < 8; ++mt){
                                f16x8 af = *(const f16x8*)(la + (kgl * 4 + quad) * 2064 + (mt * 16 + l15) * 16);
                                acc[mt][0] = MFMA16(af, w1[ckg][0], acc[mt][0]);
                                acc[mt][1] = MFMA16(af, w1[ckg][1], acc[mt][1]);
                            }
                        }
                    }
                }
                // ---- epilogue: K-reduce (kh1 -> kh0) via LDS, gather, pointwise ----
                __syncthreads();
                if (kh == 1){
                    #pragma unroll
                    for (int mt = 0; mt < 8; ++mt)
                        #pragma unroll
                        for (int nt = 0; nt < 2; ++nt){
                            int ct = nh * 32 + nt * 16 + l15;
                            *(f32x4*)(poolf + ct * 132 + mt * 16 + quad * 4) = acc[mt][nt];
                        }
                }
                __syncthreads();
                if (kh == 0){
                    #pragma unroll
                    for (int mt = 0; mt < 8; ++mt)
                        #pragma unroll
                        for (int nt = 0; nt < 2; ++nt){
                            int ct = nh * 32 + nt * 16 + l15;
                            f32x4 v = acc[mt][nt] + *(const f32x4*)(poolf + ct * 132 + mt * 16 + quad * 4);
                            *(f32x4*)(poolf + ct * 132 + mt * 16 + quad * 4) = v;
                        }
                }
                __syncthreads();
                {
                    const int m = tid >> 1, jh = tid & 1;
                    float hq[8];
                    #pragma unroll
                    for (int jj = 0; jj < 8; ++jj){
                        int j = jh * 8 + jj;
                        float gv[4];
                        #pragma unroll
                        for (int g = 0; g < 4; ++g)
                            gv[g] = poolf[(g * 16 + j) * 132 + m] + ldsBias[g * 16 + j];
                        float I = sigm(gv[0]), F = sigm(gv[1]), G = tanh_f(gv[2]), O = sigm(gv[3]);
                        float cn = F * c1[jj] + I * G;
                        c1[jj] = cn;
                        hq[jj] = O * tanh_f(cn);
                    }
                    const int kc8 = nb * 2 + jh;
                    #pragma unroll
                    for (int q = 0; q < 2; ++q){
                        U64F16 v;
                        #pragma unroll
                        for (int w = 0; w < 4; ++w) v.h[w] = (f16)hq[q * 4 + w];
                        hstore(W1p + (size_t)(kc8 * 256 + m0 + m) * 2 + q, v.q);
                    }
                }
            }
            grid_barrier(bar);
        }
    } else {
        // ======================= L0 =======================
        const int nb0 = blk - 128;
        const int j0 = nb0 * 16;
        if (tid < 64){
            int R = (tid >> 4) * 1024 + j0 + (tid & 15);
            ldsBias[tid] = bih0[R] + bhh0[R];
        }
        for (int t = tid; t < 384; t += 256){
            int ct = t / 6, i = t - ct * 6;
            int R = (ct >> 4) * 1024 + j0 + (ct & 15);
            ldsWx[t] = Wih0[(size_t)R * 6 + i];
        }
        f16x8 w0[16][2];
        {
            #pragma unroll
            for (int nt = 0; nt < 2; ++nt){
                int ct = nh * 32 + nt * 16 + l15;
                size_t Roff = (size_t)((ct >> 4) * 1024 + j0 + (ct & 15)) * 1024;
                #pragma unroll
                for (int kg = 0; kg < 16; ++kg)
                    w0[kg][nt] = cvt8(Whh0 + Roff + kh * 512 + kg * 32 + quad * 8);
            }
        }
        float c0[16];
        #pragma unroll
        for (int i = 0; i < 16; ++i) c0[i] = 0.f;

        for (int p = 0; p <= LSEQ; ++p){
            if (p < LSEQ){
                const char* P0 = (const char*)(A0 + (size_t)((p + 1) & 1) * ASZ); // h0[p-1]
                u64t* W0p = (u64t*)(A0 + (size_t)(p & 1) * ASZ);                  // h0[p]
                {   // stage x[p]
                    const float2* xp = (const float2*)(seq + (size_t)p * 1536);
                    float2* xd = (float2*)ldsX;
                    for (int i = tid; i < 768; i += 256) xd[i] = xp[i];
                }
                f32x4 acc[16][2];
                #pragma unroll
                for (int a = 0; a < 16; ++a){ acc[a][0] = (f32x4){0,0,0,0}; acc[a][1] = (f32x4){0,0,0,0}; }

                // prologue: DMA chunks 0..2 (kc8l = i, ml = tid exactly)
                #pragma unroll
                for (int n = 0; n < 3; ++n)
                    #pragma unroll
                    for (int i = 0; i < 4; ++i)
                        dma16(P0 + (size_t)(((n * 4 + i) * 256 + tid) * 16),
                              pool + n * 16448 + i * 4112 + tid * 16);
                #pragma unroll
                for (int c = 0; c < 32; ++c){
                    if (c <= 29) WAITVM8(); else if (c == 30) WAITVM4(); else WAITVM0();
                    __builtin_amdgcn_s_barrier();
                    if (c < 29){
                        const int n = c + 3;
                        const int kb = n * 4;
                        #pragma unroll
                        for (int i = 0; i < 4; ++i)
                            dma16(P0 + (size_t)(((kb + i) * 256 + tid) * 16),
                                  pool + (n & 3) * 16448 + i * 4112 + tid * 16);
                    }
                    if (kh == (c >> 4)){
                        const char* la = pool + (c & 3) * 16448;
                        const int ckg = c & 15;
                        #pragma unroll
                        for (int mt = 0; mt < 16; ++mt){
                            f16x8 af = *(const f16x8*)(la + quad * 4112 + (mt * 16 + l15) * 16);
                            acc[mt][0] = MFMA16(af, w0[ckg][0], acc[mt][0]);
                            acc[mt][1] = MFMA16(af, w0[ckg][1], acc[mt][1]);
                        }
                    }
                }
                // ---- epilogue: two m-half rounds ----
                #pragma unroll
                for (int hh = 0; hh < 2; ++hh){
                    __syncthreads();
                    if (kh == 1){
                        #pragma unroll
                        for (int mt = 8 * hh; mt < 8 * hh + 8; ++mt)
                            #pragma unroll
                            for (int nt = 0; nt < 2; ++nt){
                                int ct = nh * 32 + nt * 16 + l15;
                                *(f32x4*)(poolf + ct * 132 + (mt - 8 * hh) * 16 + quad * 4) = acc[mt][nt];
                            }
                    }
                    __syncthreads();
                    if (kh == 0){
                        #pragma unroll
                        for (int mt = 8 * hh; mt < 8 * hh + 8; ++mt)
                            #pragma unroll
                            for (int nt = 0; nt < 2; ++nt){
                                int ct = nh * 32 + nt * 16 + l15;
                                f32x4 v = acc[mt][nt] + *(const f32x4*)(poolf + ct * 132 + (mt - 8 * hh) * 16 + quad * 4);
                                *(f32x4*)(poolf + ct * 132 + (mt - 8 * hh) * 16 + quad * 4) = v;
                            }
                    }
                    __syncthreads();
                    {
                        const int ml = tid >> 1, jh = tid & 1;
                        const int ma = 128 * hh + ml;
                        float xv[6];
                        #pragma unroll
                        for (int i = 0; i < 6; ++i) xv[i] = ldsX[ma * 6 + i];
                        float hq[8];
                        #pragma unroll
                        for (int jj = 0; jj < 8; ++jj){
                            int j = jh * 8 + jj;
                            float gv[4];
                            #pragma unroll
                            for (int g = 0; g < 4; ++g){
                                float v = poolf[(g * 16 + j) * 132 + ml] + ldsBias[g * 16 + j];
                                #pragma unroll
                                for (int i = 0; i < 6; ++i) v += xv[i] * ldsWx[(g * 16 + j) * 6 + i];
                                gv[g] = v;
                            }
                            float I = sigm(gv[0]), F = sigm(gv[1]), G = tanh_f(gv[2]), O = sigm(gv[3]);
                            float cn = F * c0[hh * 8 + jj] + I * G;
                            c0[hh * 8 + jj] = cn;
                            hq[jj] = O * tanh_f(cn);
                        }
                        const int kc8 = nb0 * 2 + jh;
                        #pragma unroll
                        for (int q = 0; q < 2; ++q){
                            U64F16 v;
                            #pragma unroll
                            for (int w = 0; w < 4; ++w) v.h[w] = (f16)hq[q * 4 + w];
                            hstore(W0p + (size_t)(kc8 * 256 + ma) * 2 + q, v.q);
                        }
                    }
                }
            }
            grid_barrier(bar);
        }
        // ---- final linear on h1[511] (plane parity 1) ----
        {
            const u64t* hp = (const u64t*)(A1 + (size_t)ASZ);
            int n = nb0 * 4 + wav;
            float s = 0.f;
            #pragma unroll
            for (int u = 0; u < 2; ++u){
                int kc = u * 64 + lane;
                U2F16x8 t;
                t.q[0] = hload(hp + (size_t)(kc * 256 + n) * 2);
                t.q[1] = hload(hp + (size_t)(kc * 256 + n) * 2 + 1);
                #pragma unroll
                for (int j = 0; j < 8; ++j) s += (float)t.v[j] * linW[kc * 8 + j];
            }
            #pragma unroll
            for (int m = 32; m >= 1; m >>= 1) s += __shfl_xor(s, m, 64);
            if (lane == 0) out[n] = s + linb[0];
        }
    }
}

extern "C" void kernel_launch(void* const* d_in, const int* in_sizes, int n_in,
                              void* d_out, int out_size, void* d_ws, size_t ws_size,
                              hipStream_t stream)
{
    (void)in_sizes; (void)n_in; (void)out_size; (void)ws_size;
    const float* seq  = (const float*)d_in[0];
    const float* Wih0 = (const float*)d_in[1];
    const float* Whh0 = (const float*)d_in[2];
    const float* bih0 = (const float*)d_in[3];
    const float* bhh0 = (const float*)d_in[4];
    const float* Wih1 = (const float*)d_in[5];
    const float* Whh1 = (const float*)d_in[6];
    const float* bih1 = (const float*)d_in[7];
    const float* bhh1 = (const float*)d_in[8];
    const float* linW = (const float*)d_in[9];
    const float* linb = (const float*)d_in[10];
    float* outp = (float*)d_out;

    char* ws = (char*)d_ws;
    f16* A0p = (f16*)ws;                      // h0: [2][kc8][256 m][8] = 1 MB
    f16* A1p = (f16*)(ws + (1 << 20));        // h1: 1 MB
    int* bar = (int*)(ws + (2 << 20));        // barrier state

    (void)hipMemsetAsync(ws, 0, 2 << 20, stream);   // zero h parity planes
    (void)hipMemsetAsync(bar, 0, 256, stream);      // zero barrier

    lstm_persist<<<dim3(NBLK), dim3(256), 0, stream>>>(
        seq, Wih0, Whh0, bih0, bhh0, Wih1, Whh1, bih1, bhh1, linW, linb,
        A0p, A1p, outp, bar);
}

// Round 6
// 17886.465 us; speedup vs baseline: 1.0537x; 1.0537x over previous
//
#include <hip/hip_runtime.h>
#include <cstdint>
#include <cstddef>

#define LSEQ 512
#define NBLK 192
#define ASZ (128*256*8)   // halfs per h plane (512 KB)
#define NPLN 16           // rotation depth (write-once window)

typedef _Float16 f16;
typedef f16 f16x8 __attribute__((ext_vector_type(8)));
typedef float f32x4 __attribute__((ext_vector_type(4)));
typedef int v4i __attribute__((ext_vector_type(4)));
typedef unsigned long long u64t;

#define MFMA16(a, b, c) __builtin_amdgcn_mfma_f32_16x16x32_f16(a, b, c, 0, 0, 0)

static __device__ __forceinline__ float sigm(float x){ return 1.f/(1.f+__expf(-x)); }
static __device__ __forceinline__ float tanh_f(float x){
    x = fminf(fmaxf(x,-15.f),15.f);
    float t = __expf(-2.f*x);
    return (1.f-t)/(1.f+t);
}
static __device__ __forceinline__ f16x8 cvt8(const float* s){
    float4 a = *(const float4*)s, b = *(const float4*)(s+4);
    f16x8 v = {(f16)a.x,(f16)a.y,(f16)a.z,(f16)a.w,(f16)b.x,(f16)b.y,(f16)b.z,(f16)b.w};
    return v;
}

// ---- R6 theory: d_ws is fine-grained (MTYPE=UC) device memory -> ALL h
// accesses bypass L1/L2 regardless of aux bits, serviced on the uncached
// fabric path (~2.7 TB/s aggregate = the invariant wall of R0/R2/R3/R4/R5;
// FETCH_SIZE stays tiny because UC traffic bypasses TCC). Fix: h planes in
// ONE-TIME hipMalloc'd cacheable device memory (allocated at .so load, NOT
// inside kernel_launch -> graph-capture safe). Kernel identical to R4:
// cached loads + 16-slot write-once rotation + agent-acquire inv every 8
// steps (coherence proof: slot fill at W+1, rewrite W+16, re-read W+17;
// >=1 inv in any 8-step span). Fallback to d_ws (== R4) if alloc fails.
static __device__ __forceinline__ uint4 cl_load(const char* base, int voff){
    __amdgpu_buffer_rsrc_t srd =
        __builtin_amdgcn_make_buffer_rsrc((void*)base, (short)0, -1, 0x00020000);
    v4i r = __builtin_amdgcn_raw_buffer_load_b128(srd, voff, 0, 0);
    return __builtin_bit_cast(uint4, r);
}
// 8B IC-coherent atomic ops (h stores + final read + barrier): write-through
// to the IC coherence point, bypass L2 (proven visibility path).
static __device__ __forceinline__ u64t hload(const u64t* p){
    return __hip_atomic_load(p, __ATOMIC_RELAXED, __HIP_MEMORY_SCOPE_AGENT);
}
static __device__ __forceinline__ void hstore(u64t* p, u64t v){
    __hip_atomic_store(p, v, __ATOMIC_RELAXED, __HIP_MEMORY_SCOPE_AGENT);
}
union U64F16 { u64t q; f16 h[4]; };
union U2F16x8 { u64t q[2]; f16x8 v; };

// Single chunk barrier (R3-proven): iter = { ds_write buf[c&1]; lgkmcnt(0)+
// barrier; consume buf[c&1] }. One barrier/chunk is hazard-free; vmcnt NOT
// drained (prefetch pipeline stays live).
#define SYNC_LGKM() do { __builtin_amdgcn_s_waitcnt(0xC07F); __builtin_amdgcn_s_barrier(); } while(0)

// Single-level grid barrier (R0-proven). Agent-acquire (one buffer_inv) on
// exit every 8th step: L2-cached h lines can't outlive a rotation cycle.
static __device__ __forceinline__ void grid_barrier(int* bar, bool inv){
    __builtin_amdgcn_s_waitcnt(0x0f70);   // vmcnt(0): h stores acked at IC
    __syncthreads();
    if (threadIdx.x == 0){
        int g = __hip_atomic_load(&bar[32], __ATOMIC_RELAXED, __HIP_MEMORY_SCOPE_AGENT);
        int old = __hip_atomic_fetch_add(&bar[0], 1, __ATOMIC_RELAXED, __HIP_MEMORY_SCOPE_AGENT);
        if (old == NBLK - 1){
            __hip_atomic_store(&bar[0], 0, __ATOMIC_RELAXED, __HIP_MEMORY_SCOPE_AGENT);
            __hip_atomic_store(&bar[32], g + 1, __ATOMIC_RELAXED, __HIP_MEMORY_SCOPE_AGENT);
        } else {
            while (__hip_atomic_load(&bar[32], __ATOMIC_RELAXED, __HIP_MEMORY_SCOPE_AGENT) == g)
                __builtin_amdgcn_s_sleep(2);
        }
    }
    __syncthreads();
    if (inv) __builtin_amdgcn_fence(__ATOMIC_ACQUIRE, "agent");
}

// Plane slots: h0[t] in A0 slot (t+1)&15; h1[t] in A1 slot (t+1)&15.
// Blocks 0..127: L1 (mh=blk>>6 m-half, nb=blk&63 -> 16 j-cols x 4 gates).
// Blocks 128..191: L0 (all 256 rows, nb -> 16 j-cols x 4 gates).
// Waves: nh=wav&1 (col-half), kh=wav>>1 (K-half). Weights VGPR-resident.
// 16 chunks/step, one barrier/chunk (R3).
__global__ void __launch_bounds__(256, 1) lstm_persist(
    const float* __restrict__ seq,
    const float* __restrict__ Wih0, const float* __restrict__ Whh0,
    const float* __restrict__ bih0, const float* __restrict__ bhh0,
    const float* __restrict__ Wih1, const float* __restrict__ Whh1,
    const float* __restrict__ bih1, const float* __restrict__ bhh1,
    const float* __restrict__ linW, const float* __restrict__ linb,
    f16* __restrict__ A0, f16* __restrict__ A1, float* __restrict__ out,
    int* __restrict__ bar)
{
    __shared__ char  pool[66048] __attribute__((aligned(16)));
    __shared__ float ldsX[1536];
    __shared__ float ldsWx[384];
    __shared__ float ldsBias[64];
    float* poolf = (float*)pool;

    const int tid = threadIdx.x, lane = tid & 63, wav = tid >> 6;
    const int quad = lane >> 4, l15 = lane & 15;
    const int nh = wav & 1, kh = wav >> 1;
    const int blk = blockIdx.x;

    if (blk < 128){
        // ======================= L1 =======================
        const int mh = blk >> 6, nb = blk & 63;
        const int m0 = mh * 128, j0 = nb * 16;
        if (tid < 64){
            int R = (tid >> 4) * 1024 + j0 + (tid & 15);
            ldsBias[tid] = bih1[R] + bhh1[R];
        }
        // weights: w1[kg][nt], k = kh*1024 + kg*32 + quad*8 (kh=0 -> Wih1, kh=1 -> Whh1)
        f16x8 w1[32][2];
        {
            const float* Wsrc = kh ? Whh1 : Wih1;
            #pragma unroll
            for (int nt = 0; nt < 2; ++nt){
                int ct = nh * 32 + nt * 16 + l15;
                size_t Roff = (size_t)((ct >> 4) * 1024 + j0 + (ct & 15)) * 1024;
                #pragma unroll
                for (int kg = 0; kg < 32; ++kg)
                    w1[kg][nt] = cvt8(Wsrc + Roff + kg * 32 + quad * 8);
            }
        }
        float c1[8] = {0,0,0,0,0,0,0,0};

        for (int p = 0; p <= LSEQ; ++p){
            if (p >= 1){
                const char* P0 = (const char*)(A0 + (size_t)(p & 15) * ASZ);        // h0[p-1]
                const char* P1 = (const char*)(A1 + (size_t)((p - 1) & 15) * ASZ);  // h1[p-2]
                u64t* W1p = (u64t*)(A1 + (size_t)(p & 15) * ASZ);                   // h1[p-1]

                f32x4 acc[8][2];
                #pragma unroll
                for (int a = 0; a < 8; ++a){ acc[a][0] = (f32x4){0,0,0,0}; acc[a][1] = (f32x4){0,0,0,0}; }

                uint4 st[2][8];
                #pragma unroll
                for (int n = 0; n < 2; ++n)
                    #pragma unroll
                    for (int i = 0; i < 8; ++i){
                        int idx = i * 256 + tid, kc8l = idx >> 7, ml = idx & 127;
                        st[n][i] = cl_load(P0, ((n * 16 + kc8l) * 256 + m0 + ml) * 16);
                    }
                #pragma unroll
                for (int c = 0; c < 16; ++c){
                    {
                        char* dst = pool + (c & 1) * 33024;
                        #pragma unroll
                        for (int i = 0; i < 8; ++i){
                            int idx = i * 256 + tid, kc8l = idx >> 7, ml = idx & 127;
                            *(uint4*)(dst + kc8l * 2064 + ml * 16) = st[c & 1][i];
                        }
                    }
                    SYNC_LGKM();                              // one barrier per chunk
                    if (c < 14){
                        const int n = c + 2;
                        const char* P = (n < 8) ? P0 : P1;
                        const int kb = (n < 8) ? n * 16 : (n - 8) * 16;
                        #pragma unroll
                        for (int i = 0; i < 8; ++i){
                            int idx = i * 256 + tid, kc8l = idx >> 7, ml = idx & 127;
                            st[c & 1][i] = cl_load(P, ((kb + kc8l) * 256 + m0 + ml) * 16);
                        }
                    }
                    if (kh == ((c < 8) ? 0 : 1)){
                        const char* la = pool + (c & 1) * 33024;
                        const int cl = (c < 8) ? c : c - 8;
                        #pragma unroll
                        for (int kgl = 0; kgl < 4; ++kgl){
                            const int ckg = cl * 4 + kgl;
                            #pragma unroll
                            for (int mt = 0; mt < 8; ++mt){
                                f16x8 af = *(const f16x8*)(la + (kgl * 4 + quad) * 2064 + (mt * 16 + l15) * 16);
                                acc[mt][0] = MFMA16(af, w1[ckg][0], acc[mt][0]);
                                acc[mt][1] = MFMA16(af, w1[ckg][1], acc[mt][1]);
                            }
                        }
                    }
                }
                // ---- epilogue: K-reduce (kh1 -> kh0) via LDS, gather, pointwise ----
                __syncthreads();
                if (kh == 1){
                    #pragma unroll
                    for (int mt = 0; mt < 8; ++mt)
                        #pragma unroll
                        for (int nt = 0; nt < 2; ++nt){
                            int ct = nh * 32 + nt * 16 + l15;
                            *(f32x4*)(poolf + ct * 132 + mt * 16 + quad * 4) = acc[mt][nt];
                        }
                }
                __syncthreads();
                if (kh == 0){
                    #pragma unroll
                    for (int mt = 0; mt < 8; ++mt)
                        #pragma unroll
                        for (int nt = 0; nt < 2; ++nt){
                            int ct = nh * 32 + nt * 16 + l15;
                            f32x4 v = acc[mt][nt] + *(const f32x4*)(poolf + ct * 132 + mt * 16 + quad * 4);
                            *(f32x4*)(poolf + ct * 132 + mt * 16 + quad * 4) = v;
                        }
                }
                __syncthreads();
                {
                    const int m = tid >> 1, jh = tid & 1;
                    float hq[8];
                    #pragma unroll
                    for (int jj = 0; jj < 8; ++jj){
                        int j = jh * 8 + jj;
                        float gv[4];
                        #pragma unroll
                        for (int g = 0; g < 4; ++g)
                            gv[g] = poolf[(g * 16 + j) * 132 + m] + ldsBias[g * 16 + j];
                        float I = sigm(gv[0]), F = sigm(gv[1]), G = tanh_f(gv[2]), O = sigm(gv[3]);
                        float cn = F * c1[jj] + I * G;
                        c1[jj] = cn;
                        hq[jj] = O * tanh_f(cn);
                    }
                    const int kc8 = nb * 2 + jh;
                    #pragma unroll
                    for (int q = 0; q < 2; ++q){
                        U64F16 v;
                        #pragma unroll
                        for (int w = 0; w < 4; ++w) v.h[w] = (f16)hq[q * 4 + w];
                        hstore(W1p + (size_t)(kc8 * 256 + m0 + m) * 2 + q, v.q);
                    }
                }
            }
            grid_barrier(bar, (p & 7) == 7);
        }
    } else {
        // ======================= L0 =======================
        const int nb0 = blk - 128;
        const int j0 = nb0 * 16;
        if (tid < 64){
            int R = (tid >> 4) * 1024 + j0 + (tid & 15);
            ldsBias[tid] = bih0[R] + bhh0[R];
        }
        for (int t = tid; t < 384; t += 256){
            int ct = t / 6, i = t - ct * 6;
            int R = (ct >> 4) * 1024 + j0 + (ct & 15);
            ldsWx[t] = Wih0[(size_t)R * 6 + i];
        }
        f16x8 w0[16][2];
        {
            #pragma unroll
            for (int nt = 0; nt < 2; ++nt){
                int ct = nh * 32 + nt * 16 + l15;
                size_t Roff = (size_t)((ct >> 4) * 1024 + j0 + (ct & 15)) * 1024;
                #pragma unroll
                for (int kg = 0; kg < 16; ++kg)
                    w0[kg][nt] = cvt8(Whh0 + Roff + kh * 512 + kg * 32 + quad * 8);
            }
        }
        float c0[16];
        #pragma unroll
        for (int i = 0; i < 16; ++i) c0[i] = 0.f;

        for (int p = 0; p <= LSEQ; ++p){
            if (p < LSEQ){
                const char* P0 = (const char*)(A0 + (size_t)(p & 15) * ASZ);   // h0[p-1]
                u64t* W0p = (u64t*)(A0 + (size_t)((p + 1) & 15) * ASZ);        // h0[p]
                {   // stage x[p]
                    const float2* xp = (const float2*)(seq + (size_t)p * 1536);
                    float2* xd = (float2*)ldsX;
                    for (int i = tid; i < 768; i += 256) xd[i] = xp[i];
                }
                f32x4 acc[16][2];
                #pragma unroll
                for (int a = 0; a < 16; ++a){ acc[a][0] = (f32x4){0,0,0,0}; acc[a][1] = (f32x4){0,0,0,0}; }

                uint4 st[2][8];
                #pragma unroll
                for (int n = 0; n < 2; ++n)
                    #pragma unroll
                    for (int i = 0; i < 8; ++i){
                        int idx = i * 256 + tid, kc8l = idx >> 8, ml = idx & 255;
                        st[n][i] = cl_load(P0, ((n * 8 + kc8l) * 256 + ml) * 16);
                    }
                #pragma unroll
                for (int c = 0; c < 16; ++c){
                    {
                        char* dst = pool + (c & 1) * 32896;
                        #pragma unroll
                        for (int i = 0; i < 8; ++i){
                            int idx = i * 256 + tid, kc8l = idx >> 8, ml = idx & 255;
                            *(uint4*)(dst + kc8l * 4112 + ml * 16) = st[c & 1][i];
                        }
                    }
                    SYNC_LGKM();
                    if (c < 14){
                        const int kb = (c + 2) * 8;
                        #pragma unroll
                        for (int i = 0; i < 8; ++i){
                            int idx = i * 256 + tid, kc8l = idx >> 8, ml = idx & 255;
                            st[c & 1][i] = cl_load(P0, ((kb + kc8l) * 256 + ml) * 16);
                        }
                    }
                    if (kh == (c >> 3)){
                        const char* la = pool + (c & 1) * 32896;
                        #pragma unroll
                        for (int kgl = 0; kgl < 2; ++kgl){
                            const int ckg = (c & 7) * 2 + kgl;
                            #pragma unroll
                            for (int mt = 0; mt < 16; ++mt){
                                f16x8 af = *(const f16x8*)(la + (kgl * 4 + quad) * 4112 + (mt * 16 + l15) * 16);
                                acc[mt][0] = MFMA16(af, w0[ckg][0], acc[mt][0]);
                                acc[mt][1] = MFMA16(af, w0[ckg][1], acc[mt][1]);
                            }
                        }
                    }
                }
                // ---- epilogue: two m-half rounds ----
                #pragma unroll
                for (int hh = 0; hh < 2; ++hh){
                    __syncthreads();
                    if (kh == 1){
                        #pragma unroll
                        for (int mt = 8 * hh; mt < 8 * hh + 8; ++mt)
                            #pragma unroll
                            for (int nt = 0; nt < 2; ++nt){
                                int ct = nh * 32 + nt * 16 + l15;
                                *(f32x4*)(poolf + ct * 132 + (mt - 8 * hh) * 16 + quad * 4) = acc[mt][nt];
                            }
                    }
                    __syncthreads();
                    if (kh == 0){
                        #pragma unroll
                        for (int mt = 8 * hh; mt < 8 * hh + 8; ++mt)
                            #pragma unroll
                            for (int nt = 0; nt < 2; ++nt){
                                int ct = nh * 32 + nt * 16 + l15;
                                f32x4 v = acc[mt][nt] + *(const f32x4*)(poolf + ct * 132 + (mt - 8 * hh) * 16 + quad * 4);
                                *(f32x4*)(poolf + ct * 132 + (mt - 8 * hh) * 16 + quad * 4) = v;
                            }
                    }
                    __syncthreads();
                    {
                        const int ml = tid >> 1, jh = tid & 1;
                        const int ma = 128 * hh + ml;
                        float xv[6];
                        #pragma unroll
                        for (int i = 0; i < 6; ++i) xv[i] = ldsX[ma * 6 + i];
                        float hq[8];
                        #pragma unroll
                        for (int jj = 0; jj < 8; ++jj){
                            int j = jh * 8 + jj;
                            float gv[4];
                            #pragma unroll
                            for (int g = 0; g < 4; ++g){
                                float v = poolf[(g * 16 + j) * 132 + ml] + ldsBias[g * 16 + j];
                                #pragma unroll
                                for (int i = 0; i < 6; ++i) v += xv[i] * ldsWx[(g * 16 + j) * 6 + i];
                                gv[g] = v;
                            }
                            float I = sigm(gv[0]), F = sigm(gv[1]), G = tanh_f(gv[2]), O = sigm(gv[3]);
                            float cn = F * c0[hh * 8 + jj] + I * G;
                            c0[hh * 8 + jj] = cn;
                            hq[jj] = O * tanh_f(cn);
                        }
                        const int kc8 = nb0 * 2 + jh;
                        #pragma unroll
                        for (int q = 0; q < 2; ++q){
                            U64F16 v;
                            #pragma unroll
                            for (int w = 0; w < 4; ++w) v.h[w] = (f16)hq[q * 4 + w];
                            hstore(W0p + (size_t)(kc8 * 256 + ma) * 2 + q, v.q);
                        }
                    }
                }
            }
            grid_barrier(bar, (p & 7) == 7);
        }
        // ---- final linear on h1[511] (slot (511+1)&15 = 0) ----
        {
            const u64t* hp = (const u64t*)A1;
            int n = nb0 * 4 + wav;
            float s = 0.f;
            #pragma unroll
            for (int u = 0; u < 2; ++u){
                int kc = u * 64 + lane;
                U2F16x8 t;
                t.q[0] = hload(hp + (size_t)(kc * 256 + n) * 2);
                t.q[1] = hload(hp + (size_t)(kc * 256 + n) * 2 + 1);
                #pragma unroll
                for (int j = 0; j < 8; ++j) s += (float)t.v[j] * linW[kc * 8 + j];
            }
            #pragma unroll
            for (int m = 32; m >= 1; m >>= 1) s += __shfl_xor(s, m, 64);
            if (lane == 0) out[n] = s + linb[0];
        }
    }
}

// ---- One-time CACHEABLE device allocation at .so load (outside any graph
// capture; hipMalloc self-initializes the runtime). If this fails we fall
// back to d_ws (exact R4 behavior).
static void* g_hbuf = nullptr;
static struct HBufInit {
    HBufInit(){
        void* p = nullptr;
        if (hipMalloc(&p, (size_t)16 << 20) == hipSuccess) g_hbuf = p;
    }
} g_hbuf_init;

extern "C" void kernel_launch(void* const* d_in, const int* in_sizes, int n_in,
                              void* d_out, int out_size, void* d_ws, size_t ws_size,
                              hipStream_t stream)
{
    (void)in_sizes; (void)n_in; (void)out_size; (void)ws_size;
    const float* seq  = (const float*)d_in[0];
    const float* Wih0 = (const float*)d_in[1];
    const float* Whh0 = (const float*)d_in[2];
    const float* bih0 = (const float*)d_in[3];
    const float* bhh0 = (const float*)d_in[4];
    const float* Wih1 = (const float*)d_in[5];
    const float* Whh1 = (const float*)d_in[6];
    const float* bih1 = (const float*)d_in[7];
    const float* bhh1 = (const float*)d_in[8];
    const float* linW = (const float*)d_in[9];
    const float* linb = (const float*)d_in[10];
    float* outp = (float*)d_out;

    char* ws = (char*)d_ws;
    char* hb = g_hbuf ? (char*)g_hbuf : ws;   // cacheable if alloc succeeded
    f16* A0p = (f16*)hb;                      // h0: 16 planes x 512 KB = 8 MB
    f16* A1p = (f16*)(hb + (8 << 20));        // h1: 16 planes x 512 KB = 8 MB
    int* bar = (int*)(ws + (16 << 20));       // barrier state (stays in d_ws)

    // zero only the t=-1 slots (slot 0 of each array) + barrier
    (void)hipMemsetAsync(hb, 0, 1 << 20, stream);              // A0 slot 0
    (void)hipMemsetAsync(hb + (8 << 20), 0, 1 << 20, stream);  // A1 slot 0
    (void)hipMemsetAsync(bar, 0, 256, stream);                 // barrier

    lstm_persist<<<dim3(NBLK), dim3(256), 0, stream>>>(
        seq, Wih0, Whh0, bih0, bhh0, Wih1, Whh1, bih1, bhh1, linW, linb,
        A0p, A1p, outp, bar);
}

// Round 8
// 14321.704 us; speedup vs baseline: 1.3159x; 1.2489x over previous
//
#include <hip/hip_runtime.h>
#include <cstdint>
#include <cstddef>

#define LSEQ 512
#define NBLK 256
#define ASZ (128*256*8)   // halfs per h parity plane (512 KB)

typedef _Float16 f16;
typedef f16 f16x8 __attribute__((ext_vector_type(8)));
typedef float f32x4 __attribute__((ext_vector_type(4)));
typedef unsigned long long u64t;
typedef unsigned int u32t;

#define MFMA16(a, b, c) __builtin_amdgcn_mfma_f32_16x16x32_f16(a, b, c, 0, 0, 0)

static __device__ __forceinline__ float sigm(float x){ return 1.f/(1.f+__expf(-x)); }
static __device__ __forceinline__ float tanh_f(float x){
    x = fminf(fmaxf(x,-15.f),15.f);
    float t = __expf(-2.f*x);
    return (1.f-t)/(1.f+t);
}
static __device__ __forceinline__ f16x8 cvt8(const float* s){
    float4 a = *(const float4*)s, b = *(const float4*)(s+4);
    f16x8 v = {(f16)a.x,(f16)a.y,(f16)a.z,(f16)a.w,(f16)b.x,(f16)b.y,(f16)b.z,(f16)b.w};
    return v;
}

// ---- R8 == R7 design (R7 gave zero signal: container failed twice, no
// counters; source re-audited, no hang mechanism found -> resubmit).
// Model (fits R0-R6 within 3%): step_time = per-CU A-panel bytes / ~6.3
// B/cyc. CU vmem pipe at low occupancy is the wall — NOT IC/L2/HBM (R6:
// L2-hit service, unchanged time), NOT prefetch depth (R2), NOT barriers
// (R3), NOT VGPR spill (R5 DMA). Fix = cut bytes/CU: merged-layer blocks
// (h0[p-1] staged ONCE, feeds Whh0 AND Wih1), 4-way m-split, 256 blocks =
// all CUs, 8 waves/CU. 256 KB/block/step vs 512.
// Staging: global_load_lds (R5-proven coherent with aux 0x11 = SC0|SC1,
// served at the IC coherence point). 1 DMA instr per thread per 8 KB chunk:
// thread (wav, lane) -> kc8 row kb+wav, batch m0+lane (wave-uniform LDS
// base + lane*16, the required form).
typedef const __attribute__((address_space(1))) char gchar;
typedef __attribute__((address_space(3))) char lchar;
static __device__ __forceinline__ void dma16(const char* g, char* l){
    __builtin_amdgcn_global_load_lds((gchar*)g, (lchar*)l, 16, 0, 0x11);
}
// IC-coherent atomic ops (h stores + final read + barrier) — proven path.
static __device__ __forceinline__ u64t hload(const u64t* p){
    return __hip_atomic_load(p, __ATOMIC_RELAXED, __HIP_MEMORY_SCOPE_AGENT);
}
static __device__ __forceinline__ void hstore32(u32t* p, u32t v){
    __hip_atomic_store(p, v, __ATOMIC_RELAXED, __HIP_MEMORY_SCOPE_AGENT);
}
union U2F16x8 { u64t q[2]; f16x8 v; };

// vmcnt waits (DMA pipeline, depth 3, 1 instr/chunk/wave): own-wave wait
// BEFORE s_barrier; the barrier publishes the other 7 waves' rows.
#define WAITVM2() __builtin_amdgcn_s_waitcnt(0x0F72)
#define WAITVM1() __builtin_amdgcn_s_waitcnt(0x0F71)
#define WAITVM0() __builtin_amdgcn_s_waitcnt(0x0F70)

// Single-level grid barrier (R0-proven form). vmcnt(0) drains h stores
// (acked at IC) before arrival.
static __device__ __forceinline__ void grid_barrier(int* bar){
    WAITVM0();
    __syncthreads();
    if (threadIdx.x == 0){
        int g = __hip_atomic_load(&bar[32], __ATOMIC_RELAXED, __HIP_MEMORY_SCOPE_AGENT);
        int old = __hip_atomic_fetch_add(&bar[0], 1, __ATOMIC_RELAXED, __HIP_MEMORY_SCOPE_AGENT);
        if (old == NBLK - 1){
            __hip_atomic_store(&bar[0], 0, __ATOMIC_RELAXED, __HIP_MEMORY_SCOPE_AGENT);
            __hip_atomic_store(&bar[32], g + 1, __ATOMIC_RELAXED, __HIP_MEMORY_SCOPE_AGENT);
        } else {
            while (__hip_atomic_load(&bar[32], __ATOMIC_RELAXED, __HIP_MEMORY_SCOPE_AGENT) == g)
                __builtin_amdgcn_s_sleep(2);
        }
    }
    __syncthreads();
}

// 256 blocks: nb = blk&63 (16 j-cols x 4 gates, shared col-tiling for BOTH
// layers), mh = blk>>6 (m0 = mh*64, 64 batch rows). 512 threads = 8 waves:
// nh = wav&3 = gate index (16 cols), kh = wav>>2 splits each K=1024 at 512.
// Per step p (uniform for all blocks):
//   phase A (chunks 0-15):  stage h0[p-1] -> acc0 += Whh0, acc1 += Wih1
//   phase B (chunks 16-31): stage h1[p-2] -> acc1 += Whh1
//   epilogue: kh-reduce via LDS; L0 pointwise (p<512) -> h0[p];
//             L1 pointwise (p>=1) -> h1[p-1]. Edge steps read zeroed planes.
__global__ void __launch_bounds__(512, 2) lstm_persist(
    const float* __restrict__ seq,
    const float* __restrict__ Wih0, const float* __restrict__ Whh0,
    const float* __restrict__ bih0, const float* __restrict__ bhh0,
    const float* __restrict__ Wih1, const float* __restrict__ Whh1,
    const float* __restrict__ bih1, const float* __restrict__ bhh1,
    const float* __restrict__ linW, const float* __restrict__ linb,
    f16* __restrict__ A0, f16* __restrict__ A1, float* __restrict__ out,
    int* __restrict__ bar)
{
    __shared__ char  pool[35840] __attribute__((aligned(16))); // 4 DMA bufs x 8320 / epilogue 2x4352 f32
    __shared__ float ldsX[384];
    __shared__ float ldsWx[384];
    __shared__ float ldsB0[64];
    __shared__ float ldsB1[64];
    float* poolf = (float*)pool;

    const int tid = threadIdx.x, lane = tid & 63, wav = tid >> 6;
    const int quad = lane >> 4, l15 = lane & 15;
    const int nh = wav & 3, kh = wav >> 2;
    const int blk = blockIdx.x, nb = blk & 63, mh = blk >> 6;
    const int m0 = mh * 64, j0 = nb * 16;

    if (tid < 64){
        int R = (tid >> 4) * 1024 + j0 + (tid & 15);
        ldsB0[tid] = bih0[R] + bhh0[R];
        ldsB1[tid] = bih1[R] + bhh1[R];
    }
    if (tid < 384){
        int ct = tid / 6, i = tid - ct * 6;
        int R = (ct >> 4) * 1024 + j0 + (ct & 15);
        ldsWx[tid] = Wih0[(size_t)R * 6 + i];
    }
    // weights: per wave 16 cols (gate nh) x K-half (kh). 48 f16x8 = 192 VGPR.
    f16x8 w0[16], w1i[16], w1h[16];
    {
        const int Rw = nh * 1024 + j0 + l15;
        #pragma unroll
        for (int kg = 0; kg < 16; ++kg){
            size_t off = (size_t)Rw * 1024 + kh * 512 + kg * 32 + quad * 8;
            w0[kg]  = cvt8(Whh0 + off);
            w1i[kg] = cvt8(Wih1 + off);
            w1h[kg] = cvt8(Whh1 + off);
        }
    }
    float c0s[2] = {0.f, 0.f}, c1s[2] = {0.f, 0.f};

    for (int p = 0; p <= LSEQ; ++p){
        const char* P0 = (const char*)(A0 + (size_t)((p + 1) & 1) * ASZ); // h0[p-1]
        const char* P1 = (const char*)(A1 + (size_t)(p & 1) * ASZ);       // h1[p-2]
        f16* W0p = A0 + (size_t)(p & 1) * ASZ;                            // h0[p]
        f16* W1p = A1 + (size_t)((p + 1) & 1) * ASZ;                      // h1[p-1]

        if (p < LSEQ && tid < 384) ldsX[tid] = seq[(size_t)p * 1536 + m0 * 6 + tid];

        f32x4 acc0[4], acc1[4];
        #pragma unroll
        for (int a = 0; a < 4; ++a){ acc0[a] = (f32x4){0,0,0,0}; acc1[a] = (f32x4){0,0,0,0}; }

        // prologue: DMA chunks 0..2 (all phase A -> P0)
        #pragma unroll
        for (int n = 0; n < 3; ++n)
            dma16(P0 + (size_t)(((n * 8 + wav) * 256 + m0 + lane) * 16),
                  pool + n * 8320 + wav * 1040 + lane * 16);

        #pragma unroll
        for (int c = 0; c < 32; ++c){
            if (c <= 29) WAITVM2(); else if (c == 30) WAITVM1(); else WAITVM0();
            __builtin_amdgcn_s_barrier();            // chunk c resident for all waves
            __builtin_amdgcn_sched_barrier(0);       // no ds_read hoisting above the wait
            if (c < 29){
                const int n = c + 3;
                const char* P = (n < 16) ? P0 : P1;
                const int kb = (n & 15) * 8;
                dma16(P + (size_t)(((kb + wav) * 256 + m0 + lane) * 16),
                      pool + (n & 3) * 8320 + wav * 1040 + lane * 16);
            }
            if (((c >> 3) & 1) == kh){
                const char* la = pool + (c & 3) * 8320;
                #pragma unroll
                for (int kgl = 0; kgl < 2; ++kgl){
                    const int ckg = (c & 7) * 2 + kgl;
                    #pragma unroll
                    for (int mt = 0; mt < 4; ++mt){
                        f16x8 af = *(const f16x8*)(la + (kgl * 4 + quad) * 1040 + (mt * 16 + l15) * 16);
                        if (c < 16){
                            acc0[mt] = MFMA16(af, w0[ckg],  acc0[mt]);
                            acc1[mt] = MFMA16(af, w1i[ckg], acc1[mt]);
                        } else {
                            acc1[mt] = MFMA16(af, w1h[ckg], acc1[mt]);
                        }
                    }
                }
            }
        }
        // ---- epilogue: kh-reduce both accs via LDS, pointwise, h stores ----
        __syncthreads();
        if (kh == 1){
            #pragma unroll
            for (int mt = 0; mt < 4; ++mt){
                int o = (nh * 16 + l15) * 68 + mt * 16 + quad * 4;
                *(f32x4*)(poolf + o)        = acc0[mt];
                *(f32x4*)(poolf + 4352 + o) = acc1[mt];
            }
        }
        __syncthreads();
        if (kh == 0){
            #pragma unroll
            for (int mt = 0; mt < 4; ++mt){
                int o = (nh * 16 + l15) * 68 + mt * 16 + quad * 4;
                f32x4 v0 = acc0[mt] + *(const f32x4*)(poolf + o);
                f32x4 v1 = acc1[mt] + *(const f32x4*)(poolf + 4352 + o);
                *(f32x4*)(poolf + o)        = v0;
                *(f32x4*)(poolf + 4352 + o) = v1;
            }
        }
        __syncthreads();
        {
            const int m_l = tid & 63, jh = tid >> 6;   // 2 adjacent j per thread
            if (p < LSEQ){      // L0 pointwise -> h0[p]
                float xv[6];
                #pragma unroll
                for (int i = 0; i < 6; ++i) xv[i] = ldsX[m_l * 6 + i];
                f16 hh[2];
                #pragma unroll
                for (int s = 0; s < 2; ++s){
                    int j = jh * 2 + s;
                    float gv[4];
                    #pragma unroll
                    for (int g = 0; g < 4; ++g){
                        float v = poolf[(g * 16 + j) * 68 + m_l] + ldsB0[g * 16 + j];
                        #pragma unroll
                        for (int i = 0; i < 6; ++i) v += xv[i] * ldsWx[(g * 16 + j) * 6 + i];
                        gv[g] = v;
                    }
                    float I = sigm(gv[0]), F = sigm(gv[1]), G = tanh_f(gv[2]), O = sigm(gv[3]);
                    float cn = F * c0s[s] + I * G; c0s[s] = cn;
                    hh[s] = (f16)(O * tanh_f(cn));
                }
                const int u = j0 + jh * 2, kc8 = u >> 3, sub = u & 7;   // sub even
                union { f16 h[2]; u32t w; } pk; pk.h[0] = hh[0]; pk.h[1] = hh[1];
                hstore32((u32t*)W0p + (((kc8 * 256 + m0 + m_l) * 8 + sub) >> 1), pk.w);
            }
            if (p >= 1){        // L1 pointwise -> h1[p-1]
                f16 hh[2];
                #pragma unroll
                for (int s = 0; s < 2; ++s){
                    int j = jh * 2 + s;
                    float gv[4];
                    #pragma unroll
                    for (int g = 0; g < 4; ++g)
                        gv[g] = poolf[4352 + (g * 16 + j) * 68 + m_l] + ldsB1[g * 16 + j];
                    float I = sigm(gv[0]), F = sigm(gv[1]), G = tanh_f(gv[2]), O = sigm(gv[3]);
                    float cn = F * c1s[s] + I * G; c1s[s] = cn;
                    hh[s] = (f16)(O * tanh_f(cn));
                }
                const int u = j0 + jh * 2, kc8 = u >> 3, sub = u & 7;
                union { f16 h[2]; u32t w; } pk; pk.h[0] = hh[0]; pk.h[1] = hh[1];
                hstore32((u32t*)W1p + (((kc8 * 256 + m0 + m_l) * 8 + sub) >> 1), pk.w);
            }
        }
        grid_barrier(bar);
    }
    // ---- final linear on h1[511] (plane parity (512+1)&1 = 1) ----
    if (blk < 64 && wav < 4){
        const u64t* hp = (const u64t*)(A1 + (size_t)ASZ);
        int n = blk * 4 + wav;
        float s = 0.f;
        #pragma unroll
        for (int u = 0; u < 2; ++u){
            int kc = u * 64 + lane;
            U2F16x8 t;
            t.q[0] = hload(hp + (size_t)(kc * 256 + n) * 2);
            t.q[1] = hload(hp + (size_t)(kc * 256 + n) * 2 + 1);
            #pragma unroll
            for (int j = 0; j < 8; ++j) s += (float)t.v[j] * linW[kc * 8 + j];
        }
        #pragma unroll
        for (int m = 32; m >= 1; m >>= 1) s += __shfl_xor(s, m, 64);
        if (lane == 0) out[n] = s + linb[0];
    }
}

extern "C" void kernel_launch(void* const* d_in, const int* in_sizes, int n_in,
                              void* d_out, int out_size, void* d_ws, size_t ws_size,
                              hipStream_t stream)
{
    (void)in_sizes; (void)n_in; (void)out_size; (void)ws_size;
    const float* seq  = (const float*)d_in[0];
    const float* Wih0 = (const float*)d_in[1];
    const float* Whh0 = (const float*)d_in[2];
    const float* bih0 = (const float*)d_in[3];
    const float* bhh0 = (const float*)d_in[4];
    const float* Wih1 = (const float*)d_in[5];
    const float* Whh1 = (const float*)d_in[6];
    const float* bih1 = (const float*)d_in[7];
    const float* bhh1 = (const float*)d_in[8];
    const float* linW = (const float*)d_in[9];
    const float* linb = (const float*)d_in[10];
    float* outp = (float*)d_out;

    char* ws = (char*)d_ws;
    f16* A0p = (f16*)ws;                      // h0: [2][128 kc8][256 m][8] = 1 MB
    f16* A1p = (f16*)(ws + (1 << 20));        // h1: 1 MB
    int* bar = (int*)(ws + (2 << 20));        // barrier state

    (void)hipMemsetAsync(ws, 0, 2 << 20, stream);   // zero h parity planes
    (void)hipMemsetAsync(bar, 0, 1024, stream);     // zero barrier state

    lstm_persist<<<dim3(NBLK), dim3(512), 0, stream>>>(
        seq, Wih0, Whh0, bih0, bhh0, Wih1, Whh1, bih1, bhh1, linW, linb,
        A0p, A1p, outp, bar);
}